// Round 10
// baseline (345.606 us; speedup 1.0000x reference)
//
#include <hip/hip_runtime.h>
#include <hip/hip_bf16.h>

typedef __bf16 bf16x8 __attribute__((ext_vector_type(8)));
typedef float f32x4 __attribute__((ext_vector_type(4)));
typedef unsigned short u16;
typedef u16 u16x4 __attribute__((ext_vector_type(4)));
typedef u16 u16x8 __attribute__((ext_vector_type(8)));

#define LDA 72  // padded stride for P / transpose LDS tiles

__device__ inline u16 f2bf(float f) {
    union { float f; unsigned u; } v; v.f = f;
    unsigned r = v.u + 0x7fffu + ((v.u >> 16) & 1u);
    return (u16)(r >> 16);
}

// async global->LDS, 16B per lane; LDS dst = wave-uniform base + lane*16
#define GLD16(g, l) __builtin_amdgcn_global_load_lds( \
    (const __attribute__((address_space(1))) unsigned int*)(g), \
    (__attribute__((address_space(3))) unsigned int*)(l), 16, 0, 0)

// ---------------- prep: X convert + weight transposes ----------------
// blocks [0,4096): X fp32->bf16; [4096,4864): Wk/Wq/Wv; [4864,5120): Wo.
__global__ void k_prep(const float* __restrict__ X, u16* __restrict__ Xb,
                       const float* __restrict__ Wk, const float* __restrict__ Wq,
                       const float* __restrict__ Wv, u16* __restrict__ WT,
                       const float* __restrict__ Wo, u16* __restrict__ WoT) {
    __shared__ u16 Ls[64 * LDA];
    int u = blockIdx.x, tid = threadIdx.x;
    if (u < 4096) {
        int idx = u * 256 + tid;
        float4 v = *(const float4*)&X[(size_t)idx * 4];
        u16x4 o; o.x = f2bf(v.x); o.y = f2bf(v.y); o.z = f2bf(v.z); o.w = f2bf(v.w);
        *(u16x4*)&Xb[(size_t)idx * 4] = o;
    } else if (u < 4864) {
        int b2 = u - 4096;
        int dt = b2 & 15, h = (b2 >> 4) & 15, p = b2 >> 8;
        const float* src = (p == 0 ? Wk : p == 1 ? Wq : Wv);
        int r0 = tid >> 4, c4 = tid & 15;
        for (int j = 0; j < 4; j++) {
            int d = r0 + j * 16;
            float4 v = *(const float4*)&src[((size_t)h * 1024 + dt * 64 + d) * 64 + c4 * 4];
            u16* q = &Ls[d * LDA + c4 * 4];
            q[0] = f2bf(v.x); q[1] = f2bf(v.y); q[2] = f2bf(v.z); q[3] = f2bf(v.w);
        }
        __syncthreads();
        int nk = tid >> 2, cd = tid & 3;
        u16 tmp[16];
        for (int j = 0; j < 16; j++) tmp[j] = Ls[(cd * 16 + j) * LDA + nk];
        size_t o = ((size_t)(p * 1024 + h * 64 + nk)) * 1024 + dt * 64 + cd * 16;
        *(u16x8*)&WT[o] = *(u16x8*)&tmp[0];
        *(u16x8*)&WT[o + 8] = *(u16x8*)&tmp[8];
    } else {
        int b2 = u - 4864;
        int dt = b2 & 15, nt2 = b2 >> 4;
        int r0 = tid >> 4, c4 = tid & 15;
        for (int j = 0; j < 4; j++) {
            int d = r0 + j * 16;
            float4 v = *(const float4*)&Wo[(size_t)(dt * 64 + d) * 1024 + nt2 * 64 + c4 * 4];
            u16* q = &Ls[d * LDA + c4 * 4];
            q[0] = f2bf(v.x); q[1] = f2bf(v.y); q[2] = f2bf(v.z); q[3] = f2bf(v.w);
        }
        __syncthreads();
        int nr = tid >> 2, cd = tid & 3;
        u16 tmp[16];
        for (int j = 0; j < 16; j++) tmp[j] = Ls[(cd * 16 + j) * LDA + nr];
        size_t o = ((size_t)(nt2 * 64 + nr)) * 1024 + dt * 64 + cd * 16;
        *(u16x8*)&WoT[o] = *(u16x8*)&tmp[0];
        *(u16x8*)&WoT[o + 8] = *(u16x8*)&tmp[8];
    }
}

// ---------------- fused QKV GEMM: C[4096 m][3072 n], K=1024 ----------------
// A-operand streamed global->VGPR (register double-buffer, no LDS round-trip);
// only B staged in LDS (16 KB) via GLD16 + XOR swizzle. 128x128 tile, BK=64,
// grid (32 m-tiles, 24 n-slices), 4 waves 2x2. K/Q waves use swapped-operand
// MFMA (C^T) for packed 8B epilogue stores. LB(256,3) -> 3 blocks/CU.
__global__ __launch_bounds__(256, 3) void k_qkv(
    const u16* __restrict__ Xb, const u16* __restrict__ WT,
    const float* __restrict__ bk, const float* __restrict__ bq, const float* __restrict__ bv,
    u16* __restrict__ Kw, u16* __restrict__ Qw, u16* __restrict__ Vtw)
{
    __shared__ u16 Bs[128 * 64];
    int tid = threadIdx.x, w = tid >> 6, lane = tid & 63, quad = lane >> 4, l16 = lane & 15;
    int wm = w & 1, wn = w >> 1;
    int m0 = blockIdx.x * 128, n0 = blockIdx.y * 128;
    int rl = lane >> 3, ch = lane & 7, swch = ch ^ rl;
    const u16* Bg = WT + (size_t)(n0 + w * 32 + rl) * 1024 + swch * 8;

    // per-lane A row pointers: row = m0 + wm*64 + mt*16 + l16, col base quad*8
    const u16* Ar[4];
    for (int mt = 0; mt < 4; mt++)
        Ar[mt] = Xb + (size_t)(m0 + wm * 64 + mt * 16 + l16) * 1024 + quad * 8;

    int hb = blockIdx.y * 2 + wn;
    int p = hb >> 4, hh = hb & 15;
    bool ct = (p < 2);                        // wave-uniform: K/Q -> transposed acc

    bf16x8 cur[4][2], nxt[4][2];
    for (int mt = 0; mt < 4; mt++)
        for (int ks = 0; ks < 2; ks++)
            cur[mt][ks] = *(const bf16x8*)&Ar[mt][ks * 32];

    f32x4 acc[4][4] = {};
    for (int k0 = 0; k0 < 1024; k0 += 64) {
        for (int i = 0; i < 4; i++)
            GLD16(Bg + (size_t)i * 8 * 1024 + k0, &Bs[(w * 32 + i * 8) * 64]);
        __syncthreads();
        if (k0 < 960)   // prefetch next iter's A-frags; overlaps MFMA below
            for (int mt = 0; mt < 4; mt++)
                for (int ks = 0; ks < 2; ks++)
                    nxt[mt][ks] = *(const bf16x8*)&Ar[mt][k0 + 64 + ks * 32];
        for (int ks = 0; ks < 2; ks++) {
            bf16x8 bf[4];
            int c = (ks << 2) | quad;
            for (int nt = 0; nt < 4; nt++) {
                int row = wn * 64 + nt * 16 + l16;
                bf[nt] = *(bf16x8*)&Bs[row * 64 + (c ^ (row & 7)) * 8];
            }
            if (ct) {
                for (int mt = 0; mt < 4; mt++)
                    for (int nt = 0; nt < 4; nt++)
                        acc[mt][nt] = __builtin_amdgcn_mfma_f32_16x16x32_bf16(bf[nt], cur[mt][ks], acc[mt][nt], 0, 0, 0);
            } else {
                for (int mt = 0; mt < 4; mt++)
                    for (int nt = 0; nt < 4; nt++)
                        acc[mt][nt] = __builtin_amdgcn_mfma_f32_16x16x32_bf16(cur[mt][ks], bf[nt], acc[mt][nt], 0, 0, 0);
            }
        }
        __syncthreads();
        for (int mt = 0; mt < 4; mt++)
            for (int ks = 0; ks < 2; ks++)
                cur[mt][ks] = nxt[mt][ks];
    }
    const float* bias = (p == 0 ? bk : p == 1 ? bq : bv) + hh * 64;
    if (ct) {
        // acc[mt][nt][r] = C[m = m0+wm*64+mt*16+l16][nk = nt*16+quad*4+r]
        u16* dst = (p == 0) ? Kw : Qw;
        float sc = (p == 0) ? 0.125f : 1.0f;   // fold 1/sqrt(64) into K
        for (int mt = 0; mt < 4; mt++) {
            int m = m0 + wm * 64 + mt * 16 + l16;
            int b = m >> 10, s = m & 1023;
            size_t base = ((size_t)((b << 4) + hh) * 1024 + s) * 64;
            for (int nt = 0; nt < 4; nt++) {
                float4 bb = *(const float4*)&bias[nt * 16 + quad * 4];
                u16x4 o;
                o[0] = f2bf((acc[mt][nt][0] + bb.x) * sc);
                o[1] = f2bf((acc[mt][nt][1] + bb.y) * sc);
                o[2] = f2bf((acc[mt][nt][2] + bb.z) * sc);
                o[3] = f2bf((acc[mt][nt][3] + bb.w) * sc);
                *(u16x4*)&dst[base + nt * 16 + quad * 4] = o;
            }
        }
    } else {
        // V: transposed write [bh][nk][s]; 4 consecutive s per lane -> 8B stores
        for (int mt = 0; mt < 4; mt++)
            for (int nt = 0; nt < 4; nt++) {
                int nk = nt * 16 + l16;
                float bb = bias[nk];
                int mb = m0 + wm * 64 + mt * 16 + quad * 4;
                int b = mb >> 10, s = mb & 1023;
                u16x4 o;
                for (int r = 0; r < 4; r++) o[r] = f2bf(acc[mt][nt][r] + bb);
                *(u16x4*)&Vtw[((size_t)((b << 4) + hh) * 64 + nk) * 1024 + s] = o;
            }
    }
}

// ---------------- flash attention (R6-verified) ----------------
// grid (64 bh, 8 q-tiles): id%8 = bh%8 -> XCD-local K/V.
// Double-buffered GLD16 staging; fixed-max softmax exp(s-16); MFMA row-sum.
__global__ __launch_bounds__(256) void k_attn(
    const u16* __restrict__ Qw, const u16* __restrict__ Kw,
    const u16* __restrict__ Vtw, u16* __restrict__ Zw)
{
    __shared__ u16 Ks[2][64 * 64];
    __shared__ u16 Vs[2][64 * 64];
    __shared__ u16 Ps[4 * 2 * 16 * LDA];
    int tid = threadIdx.x, w = tid >> 6, lane = tid & 63, quad = lane >> 4, l16 = lane & 15;
    int bh = blockIdx.x, q0 = blockIdx.y * 128;
    const u16* Qp = Qw + (size_t)bh * 65536;
    int rl = lane >> 3, ch = lane & 7, swch = ch ^ rl;
    const u16* Kg = Kw + (size_t)bh * 65536 + (w * 16 + rl) * 64 + swch * 8;
    const u16* Vg = Vtw + (size_t)bh * 65536 + (size_t)(w * 16 + rl) * 1024 + swch * 8;

    bf16x8 aq[2][2];
    for (int g = 0; g < 2; g++)
        for (int ks = 0; ks < 2; ks++)
            aq[g][ks] = *(const bf16x8*)&Qp[(size_t)(q0 + w * 32 + g * 16 + l16) * 64 + ks * 32 + quad * 8];

    f32x4 acc[2][4] = {};
    f32x4 accs[2] = {};
    __bf16 onev = (__bf16)1.0f;
    bf16x8 ones = {onev, onev, onev, onev, onev, onev, onev, onev};
    u16* Pw0 = Ps + (w * 2) * 16 * LDA;
    u16* Pw1 = Pw0 + 16 * LDA;

#define STAGE(st, buf) { int s0_ = (st) * 64; \
    for (int i = 0; i < 2; i++) { \
        GLD16(Kg + (s0_ + i * 8) * 64, &Ks[buf][(w * 16 + i * 8) * 64]); \
        GLD16(Vg + (size_t)i * 8 * 1024 + s0_, &Vs[buf][(w * 16 + i * 8) * 64]); } }

    STAGE(0, 0);
    for (int st = 0; st < 16; st++) {
        int buf = st & 1;
        __syncthreads();
        if (st < 15) STAGE(st + 1, buf ^ 1);
        f32x4 sacc[2][4] = {};
        for (int ks = 0; ks < 2; ks++) {
            int c = (ks << 2) | quad;
            for (int nt = 0; nt < 4; nt++) {
                int row = nt * 16 + l16;
                bf16x8 kf = *(bf16x8*)&Ks[buf][row * 64 + (c ^ (row & 7)) * 8];
                sacc[0][nt] = __builtin_amdgcn_mfma_f32_16x16x32_bf16(aq[0][ks], kf, sacc[0][nt], 0, 0, 0);
                sacc[1][nt] = __builtin_amdgcn_mfma_f32_16x16x32_bf16(aq[1][ks], kf, sacc[1][nt], 0, 0, 0);
            }
        }
        for (int g = 0; g < 2; g++) {
            u16* Pw = g ? Pw1 : Pw0;
            for (int nt = 0; nt < 4; nt++)
                for (int r = 0; r < 4; r++) {
                    float p = __builtin_exp2f(__builtin_fmaf(sacc[g][nt][r], 1.44269504f, -23.0831206f));
                    union { float f; unsigned u; } cv; cv.f = p;
                    Pw[(quad * 4 + r) * LDA + nt * 16 + l16] = (u16)((cv.u + 0x8000u) >> 16);
                }
        }
        for (int ks2 = 0; ks2 < 2; ks2++) {
            int c = (ks2 << 2) | quad;
            bf16x8 ap0 = *(bf16x8*)&Pw0[l16 * LDA + ks2 * 32 + quad * 8];
            bf16x8 ap1 = *(bf16x8*)&Pw1[l16 * LDA + ks2 * 32 + quad * 8];
            accs[0] = __builtin_amdgcn_mfma_f32_16x16x32_bf16(ap0, ones, accs[0], 0, 0, 0);
            accs[1] = __builtin_amdgcn_mfma_f32_16x16x32_bf16(ap1, ones, accs[1], 0, 0, 0);
            for (int ntv = 0; ntv < 4; ntv++) {
                int row = ntv * 16 + l16;
                bf16x8 vf = *(bf16x8*)&Vs[buf][row * 64 + (c ^ (row & 7)) * 8];
                acc[0][ntv] = __builtin_amdgcn_mfma_f32_16x16x32_bf16(ap0, vf, acc[0][ntv], 0, 0, 0);
                acc[1][ntv] = __builtin_amdgcn_mfma_f32_16x16x32_bf16(ap1, vf, acc[1][ntv], 0, 0, 0);
            }
        }
    }
#undef STAGE
    int b = bh >> 4, h = bh & 15;
    for (int g = 0; g < 2; g++)
        for (int r = 0; r < 4; r++) {
            float inv = 1.f / accs[g][r];
            int q = q0 + w * 32 + g * 16 + quad * 4 + r;
            for (int ntv = 0; ntv < 4; ntv++)
                Zw[((size_t)(b * 1024 + q)) * 1024 + h * 64 + ntv * 16 + l16] = f2bf(acc[g][ntv][r] * inv);
        }
}

// ---------------- output projection: 64x128 tiles, 512 blocks ----------------
__global__ __launch_bounds__(256) void k_oproj(
    const u16* __restrict__ Zw, const u16* __restrict__ WoT, const float* __restrict__ bo,
    const float* __restrict__ X, float* __restrict__ out)
{
    __shared__ u16 As[64 * 64];
    __shared__ u16 Bs[128 * 64];
    int tid = threadIdx.x, w = tid >> 6, lane = tid & 63, quad = lane >> 4, l16 = lane & 15;
    int wm = w & 1, wn = w >> 1;
    int m0 = blockIdx.x * 64, n0 = blockIdx.y * 128;
    int rl = lane >> 3, ch = lane & 7, swch = ch ^ rl;
    const u16* Ag = Zw + (size_t)(m0 + w * 16 + rl) * 1024 + swch * 8;
    const u16* Bg = WoT + (size_t)(n0 + w * 32 + rl) * 1024 + swch * 8;

    f32x4 acc[2][4] = {};
    for (int k0 = 0; k0 < 1024; k0 += 64) {
        for (int i = 0; i < 2; i++)
            GLD16(Ag + (size_t)i * 8 * 1024 + k0, &As[(w * 16 + i * 8) * 64]);
        for (int i = 0; i < 4; i++)
            GLD16(Bg + (size_t)i * 8 * 1024 + k0, &Bs[(w * 32 + i * 8) * 64]);
        __syncthreads();
        for (int ks = 0; ks < 2; ks++) {
            bf16x8 af[2], bf[4];
            int c = (ks << 2) | quad;
            for (int mt = 0; mt < 2; mt++) {
                int row = wm * 32 + mt * 16 + l16;
                af[mt] = *(bf16x8*)&As[row * 64 + (c ^ (row & 7)) * 8];
            }
            for (int nt = 0; nt < 4; nt++) {
                int row = wn * 64 + nt * 16 + l16;
                bf[nt] = *(bf16x8*)&Bs[row * 64 + (c ^ (row & 7)) * 8];
            }
            for (int mt = 0; mt < 2; mt++)
                for (int nt = 0; nt < 4; nt++)
                    acc[mt][nt] = __builtin_amdgcn_mfma_f32_16x16x32_bf16(af[mt], bf[nt], acc[mt][nt], 0, 0, 0);
        }
        __syncthreads();
    }
    for (int mt = 0; mt < 2; mt++)
        for (int nt = 0; nt < 4; nt++) {
            int n = n0 + wn * 64 + nt * 16 + l16;
            float bb = bo[n];
            for (int r = 0; r < 4; r++) {
                int m = m0 + wm * 32 + mt * 16 + quad * 4 + r;
                out[(size_t)m * 1024 + n] = acc[mt][nt][r] + bb + X[(size_t)m * 1024 + n];
            }
        }
}

extern "C" void kernel_launch(void* const* d_in, const int* in_sizes, int n_in,
                              void* d_out, int out_size, void* d_ws, size_t ws_size,
                              hipStream_t stream) {
    const float* X  = (const float*)d_in[0];
    const float* Wk = (const float*)d_in[1];
    const float* bk = (const float*)d_in[2];
    const float* Wq = (const float*)d_in[3];
    const float* bq = (const float*)d_in[4];
    const float* Wv = (const float*)d_in[5];
    const float* bv = (const float*)d_in[6];
    const float* Wo = (const float*)d_in[7];
    const float* bo = (const float*)d_in[8];
    u16* ws = (u16*)d_ws;
    const size_t NQ = 4u * 16u * 1024u * 64u;   // 4,194,304 elems
    u16* Qw  = ws;
    u16* Kw  = ws + NQ;
    u16* Vtw = ws + 2 * NQ;
    u16* Zw  = ws + 3 * NQ;
    u16* WT  = ws + 4 * NQ;            // [3072 n][1024 k] bf16 (K,Q,V packed)
    u16* WoT = WT + 3 * 1048576;       // [1024 n][1024 k]
    u16* Xb  = WoT + 1048576;          // X bf16
    float* outp = (float*)d_out;

    k_prep <<<5120, 256, 0, stream>>>(X, Xb, Wk, Wq, Wv, WT, Wo, WoT);
    k_qkv  <<<dim3(32, 24), 256, 0, stream>>>(Xb, WT, bk, bq, bv, Kw, Qw, Vtw);
    k_attn <<<dim3(64, 8), 256, 0, stream>>>(Qw, Kw, Vtw, Zw);
    k_oproj<<<dim3(64, 8), 256, 0, stream>>>(Zw, WoT, bo, X, outp);
}

// Round 12
// 192.933 us; speedup vs baseline: 1.7913x; 1.7913x over previous
//
#include <hip/hip_runtime.h>
#include <hip/hip_bf16.h>

typedef __bf16 bf16x8 __attribute__((ext_vector_type(8)));
typedef float f32x4 __attribute__((ext_vector_type(4)));
typedef unsigned short u16;
typedef u16 u16x4 __attribute__((ext_vector_type(4)));
typedef u16 u16x8 __attribute__((ext_vector_type(8)));

#define LDA 72  // padded stride for P / transpose LDS tiles

__device__ inline u16 f2bf(float f) {
    union { float f; unsigned u; } v; v.f = f;
    unsigned r = v.u + 0x7fffu + ((v.u >> 16) & 1u);
    return (u16)(r >> 16);
}

// async global->LDS, 16B per lane; LDS dst = wave-uniform base + lane*16
#define GLD16(g, l) __builtin_amdgcn_global_load_lds( \
    (const __attribute__((address_space(1))) unsigned int*)(g), \
    (__attribute__((address_space(3))) unsigned int*)(l), 16, 0, 0)

// ---------------- prep: X convert + weight transposes ----------------
// blocks [0,4096): X fp32->bf16; [4096,4864): Wk/Wq/Wv; [4864,5120): Wo.
__global__ void k_prep(const float* __restrict__ X, u16* __restrict__ Xb,
                       const float* __restrict__ Wk, const float* __restrict__ Wq,
                       const float* __restrict__ Wv, u16* __restrict__ WT,
                       const float* __restrict__ Wo, u16* __restrict__ WoT) {
    __shared__ u16 Ls[64 * LDA];
    int u = blockIdx.x, tid = threadIdx.x;
    if (u < 4096) {
        int idx = u * 256 + tid;
        float4 v = *(const float4*)&X[(size_t)idx * 4];
        u16x4 o; o.x = f2bf(v.x); o.y = f2bf(v.y); o.z = f2bf(v.z); o.w = f2bf(v.w);
        *(u16x4*)&Xb[(size_t)idx * 4] = o;
    } else if (u < 4864) {
        int b2 = u - 4096;
        int dt = b2 & 15, h = (b2 >> 4) & 15, p = b2 >> 8;
        const float* src = (p == 0 ? Wk : p == 1 ? Wq : Wv);
        int r0 = tid >> 4, c4 = tid & 15;
        for (int j = 0; j < 4; j++) {
            int d = r0 + j * 16;
            float4 v = *(const float4*)&src[((size_t)h * 1024 + dt * 64 + d) * 64 + c4 * 4];
            u16* q = &Ls[d * LDA + c4 * 4];
            q[0] = f2bf(v.x); q[1] = f2bf(v.y); q[2] = f2bf(v.z); q[3] = f2bf(v.w);
        }
        __syncthreads();
        int nk = tid >> 2, cd = tid & 3;
        u16 tmp[16];
        for (int j = 0; j < 16; j++) tmp[j] = Ls[(cd * 16 + j) * LDA + nk];
        size_t o = ((size_t)(p * 1024 + h * 64 + nk)) * 1024 + dt * 64 + cd * 16;
        *(u16x8*)&WT[o] = *(u16x8*)&tmp[0];
        *(u16x8*)&WT[o + 8] = *(u16x8*)&tmp[8];
    } else {
        int b2 = u - 4864;
        int dt = b2 & 15, nt2 = b2 >> 4;
        int r0 = tid >> 4, c4 = tid & 15;
        for (int j = 0; j < 4; j++) {
            int d = r0 + j * 16;
            float4 v = *(const float4*)&Wo[(size_t)(dt * 64 + d) * 1024 + nt2 * 64 + c4 * 4];
            u16* q = &Ls[d * LDA + c4 * 4];
            q[0] = f2bf(v.x); q[1] = f2bf(v.y); q[2] = f2bf(v.z); q[3] = f2bf(v.w);
        }
        __syncthreads();
        int nr = tid >> 2, cd = tid & 3;
        u16 tmp[16];
        for (int j = 0; j < 16; j++) tmp[j] = Ls[(cd * 16 + j) * LDA + nr];
        size_t o = ((size_t)(nt2 * 64 + nr)) * 1024 + dt * 64 + cd * 16;
        *(u16x8*)&WoT[o] = *(u16x8*)&tmp[0];
        *(u16x8*)&WoT[o + 8] = *(u16x8*)&tmp[8];
    }
}

// ---------------- fused QKV GEMM (R9-verified, 43.9 us) ----------------
// 128x128 tile, BK=64, GLD16 staging, XOR-swizzled unpadded LDS.
// grid (32 m-tiles, 24 n-slices), 4 waves 2x2. K/Q waves: swapped-operand
// MFMA (C^T) -> packed 8B epilogue stores. LB(256,3) -> 3 blocks/CU.
__global__ __launch_bounds__(256, 3) void k_qkv(
    const u16* __restrict__ Xb, const u16* __restrict__ WT,
    const float* __restrict__ bk, const float* __restrict__ bq, const float* __restrict__ bv,
    u16* __restrict__ Kw, u16* __restrict__ Qw, u16* __restrict__ Vtw)
{
    __shared__ u16 As[128 * 64];
    __shared__ u16 Bs[128 * 64];
    int tid = threadIdx.x, w = tid >> 6, lane = tid & 63, quad = lane >> 4, l16 = lane & 15;
    int wm = w & 1, wn = w >> 1;
    int m0 = blockIdx.x * 128, n0 = blockIdx.y * 128;
    int rl = lane >> 3, ch = lane & 7, swch = ch ^ rl;
    const u16* Ag = Xb + (size_t)(m0 + w * 32 + rl) * 1024 + swch * 8;
    const u16* Bg = WT + (size_t)(n0 + w * 32 + rl) * 1024 + swch * 8;

    int hb = blockIdx.y * 2 + wn;
    int p = hb >> 4, hh = hb & 15;
    bool ct = (p < 2);                        // wave-uniform: K/Q -> transposed acc

    f32x4 acc[4][4] = {};
    for (int k0 = 0; k0 < 1024; k0 += 64) {
        for (int i = 0; i < 4; i++) {
            GLD16(Ag + (size_t)i * 8 * 1024 + k0, &As[(w * 32 + i * 8) * 64]);
            GLD16(Bg + (size_t)i * 8 * 1024 + k0, &Bs[(w * 32 + i * 8) * 64]);
        }
        __syncthreads();
        for (int ks = 0; ks < 2; ks++) {
            bf16x8 af[4], bf[4];
            int c = (ks << 2) | quad;
            for (int mt = 0; mt < 4; mt++) {
                int row = wm * 64 + mt * 16 + l16;
                af[mt] = *(bf16x8*)&As[row * 64 + (c ^ (row & 7)) * 8];
            }
            for (int nt = 0; nt < 4; nt++) {
                int row = wn * 64 + nt * 16 + l16;
                bf[nt] = *(bf16x8*)&Bs[row * 64 + (c ^ (row & 7)) * 8];
            }
            if (ct) {
                for (int mt = 0; mt < 4; mt++)
                    for (int nt = 0; nt < 4; nt++)
                        acc[mt][nt] = __builtin_amdgcn_mfma_f32_16x16x32_bf16(bf[nt], af[mt], acc[mt][nt], 0, 0, 0);
            } else {
                for (int mt = 0; mt < 4; mt++)
                    for (int nt = 0; nt < 4; nt++)
                        acc[mt][nt] = __builtin_amdgcn_mfma_f32_16x16x32_bf16(af[mt], bf[nt], acc[mt][nt], 0, 0, 0);
            }
        }
        __syncthreads();
    }
    const float* bias = (p == 0 ? bk : p == 1 ? bq : bv) + hh * 64;
    if (ct) {
        // acc[mt][nt][r] = C[m = m0+wm*64+mt*16+l16][nk = nt*16+quad*4+r]
        u16* dst = (p == 0) ? Kw : Qw;
        float sc = (p == 0) ? 0.125f : 1.0f;   // fold 1/sqrt(64) into K
        for (int mt = 0; mt < 4; mt++) {
            int m = m0 + wm * 64 + mt * 16 + l16;
            int b = m >> 10, s = m & 1023;
            size_t base = ((size_t)((b << 4) + hh) * 1024 + s) * 64;
            for (int nt = 0; nt < 4; nt++) {
                float4 bb = *(const float4*)&bias[nt * 16 + quad * 4];
                u16x4 o;
                o[0] = f2bf((acc[mt][nt][0] + bb.x) * sc);
                o[1] = f2bf((acc[mt][nt][1] + bb.y) * sc);
                o[2] = f2bf((acc[mt][nt][2] + bb.z) * sc);
                o[3] = f2bf((acc[mt][nt][3] + bb.w) * sc);
                *(u16x4*)&dst[base + nt * 16 + quad * 4] = o;
            }
        }
    } else {
        // V: transposed write [bh][nk][s]; 4 consecutive s per lane -> 8B stores
        for (int mt = 0; mt < 4; mt++)
            for (int nt = 0; nt < 4; nt++) {
                int nk = nt * 16 + l16;
                float bb = bias[nk];
                int mb = m0 + wm * 64 + mt * 16 + quad * 4;
                int b = mb >> 10, s = mb & 1023;
                u16x4 o;
                for (int r = 0; r < 4; r++) o[r] = f2bf(acc[mt][nt][r] + bb);
                *(u16x4*)&Vtw[((size_t)((b << 4) + hh) * 64 + nk) * 1024 + s] = o;
            }
    }
}

// ---------------- flash attention v4: 64 q/block, 3 blocks/CU ----------------
// grid (64 bh, 16 q-tiles) = 1024 blocks; id%8 = bh%8 -> XCD-local K/V.
// One q-set per wave -> Ps 9 KB, LDS total 41 KB -> 3 blocks/CU (12 waves).
// Double-buffered GLD16 staging; fixed-max softmax exp(s-16); MFMA row-sum.
__global__ __launch_bounds__(256, 3) void k_attn(
    const u16* __restrict__ Qw, const u16* __restrict__ Kw,
    const u16* __restrict__ Vtw, u16* __restrict__ Zw)
{
    __shared__ u16 Ks[2][64 * 64];
    __shared__ u16 Vs[2][64 * 64];
    __shared__ u16 Ps[4 * 16 * LDA];
    int tid = threadIdx.x, w = tid >> 6, lane = tid & 63, quad = lane >> 4, l16 = lane & 15;
    int bh = blockIdx.x, q0 = blockIdx.y * 64;
    const u16* Qp = Qw + (size_t)bh * 65536;
    int rl = lane >> 3, ch = lane & 7, swch = ch ^ rl;
    const u16* Kg = Kw + (size_t)bh * 65536 + (w * 16 + rl) * 64 + swch * 8;
    const u16* Vg = Vtw + (size_t)bh * 65536 + (size_t)(w * 16 + rl) * 1024 + swch * 8;

    bf16x8 aq[2];
    for (int ks = 0; ks < 2; ks++)
        aq[ks] = *(const bf16x8*)&Qp[(size_t)(q0 + w * 16 + l16) * 64 + ks * 32 + quad * 8];

    f32x4 acc[4] = {};
    f32x4 accs = {};
    __bf16 onev = (__bf16)1.0f;
    bf16x8 ones = {onev, onev, onev, onev, onev, onev, onev, onev};
    u16* Pw = Ps + w * 16 * LDA;

#define STAGE(st, buf) { int s0_ = (st) * 64; \
    for (int i = 0; i < 2; i++) { \
        GLD16(Kg + (s0_ + i * 8) * 64, &Ks[buf][(w * 16 + i * 8) * 64]); \
        GLD16(Vg + (size_t)i * 8 * 1024 + s0_, &Vs[buf][(w * 16 + i * 8) * 64]); } }

    STAGE(0, 0);
    for (int st = 0; st < 16; st++) {
        int buf = st & 1;
        __syncthreads();
        if (st < 15) STAGE(st + 1, buf ^ 1);
        f32x4 sacc[4] = {};
        for (int ks = 0; ks < 2; ks++) {
            int c = (ks << 2) | quad;
            for (int nt = 0; nt < 4; nt++) {
                int row = nt * 16 + l16;
                bf16x8 kf = *(bf16x8*)&Ks[buf][row * 64 + (c ^ (row & 7)) * 8];
                sacc[nt] = __builtin_amdgcn_mfma_f32_16x16x32_bf16(aq[ks], kf, sacc[nt], 0, 0, 0);
            }
        }
        for (int nt = 0; nt < 4; nt++)
            for (int r = 0; r < 4; r++) {
                float p = __builtin_exp2f(__builtin_fmaf(sacc[nt][r], 1.44269504f, -23.0831206f));
                union { float f; unsigned u; } cv; cv.f = p;
                Pw[(quad * 4 + r) * LDA + nt * 16 + l16] = (u16)((cv.u + 0x8000u) >> 16);
            }
        for (int ks2 = 0; ks2 < 2; ks2++) {
            int c = (ks2 << 2) | quad;
            bf16x8 ap = *(bf16x8*)&Pw[l16 * LDA + ks2 * 32 + quad * 8];
            accs = __builtin_amdgcn_mfma_f32_16x16x32_bf16(ap, ones, accs, 0, 0, 0);
            for (int ntv = 0; ntv < 4; ntv++) {
                int row = ntv * 16 + l16;
                bf16x8 vf = *(bf16x8*)&Vs[buf][row * 64 + (c ^ (row & 7)) * 8];
                acc[ntv] = __builtin_amdgcn_mfma_f32_16x16x32_bf16(ap, vf, acc[ntv], 0, 0, 0);
            }
        }
    }
#undef STAGE
    int b = bh >> 4, h = bh & 15;
    for (int r = 0; r < 4; r++) {
        float inv = 1.f / accs[r];
        int q = q0 + w * 16 + quad * 4 + r;
        for (int ntv = 0; ntv < 4; ntv++)
            Zw[((size_t)(b * 1024 + q)) * 1024 + h * 64 + ntv * 16 + l16] = f2bf(acc[ntv][r] * inv);
    }
}

// ---------------- output projection: 64x128 tiles, 512 blocks ----------------
__global__ __launch_bounds__(256) void k_oproj(
    const u16* __restrict__ Zw, const u16* __restrict__ WoT, const float* __restrict__ bo,
    const float* __restrict__ X, float* __restrict__ out)
{
    __shared__ u16 As[64 * 64];
    __shared__ u16 Bs[128 * 64];
    int tid = threadIdx.x, w = tid >> 6, lane = tid & 63, quad = lane >> 4, l16 = lane & 15;
    int wm = w & 1, wn = w >> 1;
    int m0 = blockIdx.x * 64, n0 = blockIdx.y * 128;
    int rl = lane >> 3, ch = lane & 7, swch = ch ^ rl;
    const u16* Ag = Zw + (size_t)(m0 + w * 16 + rl) * 1024 + swch * 8;
    const u16* Bg = WoT + (size_t)(n0 + w * 32 + rl) * 1024 + swch * 8;

    f32x4 acc[2][4] = {};
    for (int k0 = 0; k0 < 1024; k0 += 64) {
        for (int i = 0; i < 2; i++)
            GLD16(Ag + (size_t)i * 8 * 1024 + k0, &As[(w * 16 + i * 8) * 64]);
        for (int i = 0; i < 4; i++)
            GLD16(Bg + (size_t)i * 8 * 1024 + k0, &Bs[(w * 32 + i * 8) * 64]);
        __syncthreads();
        for (int ks = 0; ks < 2; ks++) {
            bf16x8 af[2], bf[4];
            int c = (ks << 2) | quad;
            for (int mt = 0; mt < 2; mt++) {
                int row = wm * 32 + mt * 16 + l16;
                af[mt] = *(bf16x8*)&As[row * 64 + (c ^ (row & 7)) * 8];
            }
            for (int nt = 0; nt < 4; nt++) {
                int row = wn * 64 + nt * 16 + l16;
                bf[nt] = *(bf16x8*)&Bs[row * 64 + (c ^ (row & 7)) * 8];
            }
            for (int mt = 0; mt < 2; mt++)
                for (int nt = 0; nt < 4; nt++)
                    acc[mt][nt] = __builtin_amdgcn_mfma_f32_16x16x32_bf16(af[mt], bf[nt], acc[mt][nt], 0, 0, 0);
        }
        __syncthreads();
    }
    for (int mt = 0; mt < 2; mt++)
        for (int nt = 0; nt < 4; nt++) {
            int n = n0 + wn * 64 + nt * 16 + l16;
            float bb = bo[n];
            for (int r = 0; r < 4; r++) {
                int m = m0 + wm * 32 + mt * 16 + quad * 4 + r;
                out[(size_t)m * 1024 + n] = acc[mt][nt][r] + bb + X[(size_t)m * 1024 + n];
            }
        }
}

extern "C" void kernel_launch(void* const* d_in, const int* in_sizes, int n_in,
                              void* d_out, int out_size, void* d_ws, size_t ws_size,
                              hipStream_t stream) {
    const float* X  = (const float*)d_in[0];
    const float* Wk = (const float*)d_in[1];
    const float* bk = (const float*)d_in[2];
    const float* Wq = (const float*)d_in[3];
    const float* bq = (const float*)d_in[4];
    const float* Wv = (const float*)d_in[5];
    const float* bv = (const float*)d_in[6];
    const float* Wo = (const float*)d_in[7];
    const float* bo = (const float*)d_in[8];
    u16* ws = (u16*)d_ws;
    const size_t NQ = 4u * 16u * 1024u * 64u;   // 4,194,304 elems
    u16* Qw  = ws;
    u16* Kw  = ws + NQ;
    u16* Vtw = ws + 2 * NQ;
    u16* Zw  = ws + 3 * NQ;
    u16* WT  = ws + 4 * NQ;            // [3072 n][1024 k] bf16 (K,Q,V packed)
    u16* WoT = WT + 3 * 1048576;       // [1024 n][1024 k]
    u16* Xb  = WoT + 1048576;          // X bf16
    float* outp = (float*)d_out;

    k_prep <<<5120, 256, 0, stream>>>(X, Xb, Wk, Wq, Wv, WT, Wo, WoT);
    k_qkv  <<<dim3(32, 24), 256, 0, stream>>>(Xb, WT, bk, bq, bv, Kw, Qw, Vtw);
    k_attn <<<dim3(64, 16), 256, 0, stream>>>(Qw, Kw, Vtw, Zw);
    k_oproj<<<dim3(64, 8), 256, 0, stream>>>(Zw, WoT, bo, X, outp);
}